// Round 1
// baseline (1151.422 us; speedup 1.0000x reference)
//
#include <hip/hip_runtime.h>
#include <hip/hip_bf16.h>

// clusterLayer: q = rownorm( 1 / (1 + ||x||^2 + ||c||^2 - 2 x.cT) )
// N=524288 rows, K=256 clusters, D=256. fp32 in/out; bf16 MFMA for the
// cross term; norms kept fp32 (computed during staging conversion).

#define DD 256   // feature dim (reduction)
#define KC 256   // clusters (output cols)
#define BM 128   // rows per block
#define BK 32    // K-step
#define NSTEP (DD / BK)

typedef __attribute__((ext_vector_type(4))) float  f32x4;
typedef __attribute__((ext_vector_type(8))) short  bf16x8;

__device__ __forceinline__ short f2bf(float f) {
    // round-to-nearest-even fp32 -> bf16
    union { float f; unsigned u; } v; v.f = f;
    unsigned r = (v.u + 0x7fffu + ((v.u >> 16) & 1u)) >> 16;
    return (short)r;
}

__device__ __forceinline__ f32x4 ld4(const float* p) {
    return *(const f32x4*)p;
}

__device__ __forceinline__ void cvt_sq(const f32x4 x, const f32x4 y,
                                       bf16x8& o, float& s) {
    o[0] = f2bf(x[0]); o[1] = f2bf(x[1]); o[2] = f2bf(x[2]); o[3] = f2bf(x[3]);
    o[4] = f2bf(y[0]); o[5] = f2bf(y[1]); o[6] = f2bf(y[2]); o[7] = f2bf(y[3]);
    s += x[0]*x[0] + x[1]*x[1] + x[2]*x[2] + x[3]*x[3]
       + y[0]*y[0] + y[1]*y[1] + y[2]*y[2] + y[3]*y[3];
}

__global__ __launch_bounds__(512, 4)
void cluster_q_kernel(const float* __restrict__ ctx,
                      const float* __restrict__ clus,
                      float* __restrict__ out) {
    __shared__ short As[BM][BK];       // 8 KiB  (bf16 context tile)
    __shared__ short Bs[KC][BK];       // 16 KiB (bf16 clusters tile)
    __shared__ float x2s[BM];          // per-row |x|^2
    __shared__ float c2s[KC];          // per-cluster |c|^2
    __shared__ float rowsum4[BM][4];   // per-wave-column partial row sums

    const int t    = threadIdx.x;
    const int lane = t & 63;
    const int w    = t >> 6;           // wave id 0..7
    const int wm   = w >> 2;           // 0..1  (M position)
    const int wn   = w & 3;            // 0..3  (N position)
    const int g    = lane >> 4;        // 0..3  (k-group)
    const int l16  = lane & 15;        // 0..15 (col within fragment)

    const size_t row0 = (size_t)blockIdx.x * BM;

    // staging assignment (fixed rows per thread across all K-steps)
    const int arow = t >> 2;           // 0..127, 4 threads/row
    const int ac8  = (t & 3) * 8;      // 8 cols each
    const int brow = t >> 1;           // 0..255, 2 threads/row
    const int bc16 = (t & 1) * 16;     // 16 cols each

    const float* agp = ctx  + (row0 + (size_t)arow) * DD + ac8;
    const float* bgp = clus + (size_t)brow * DD + bc16;

    float accA = 0.f;   // sum of squares for context row slice
    float accB = 0.f;   // sum of squares for cluster row slice

    f32x4 acc[4][4];
#pragma unroll
    for (int i = 0; i < 4; ++i)
#pragma unroll
        for (int j = 0; j < 4; ++j)
            acc[i][j] = (f32x4)0.f;

    // prologue: load k-step 0
    f32x4 a0 = ld4(agp), a1 = ld4(agp + 4);
    f32x4 b0 = ld4(bgp),     b1 = ld4(bgp + 4),
          b2 = ld4(bgp + 8), b3 = ld4(bgp + 12);

#pragma unroll
    for (int ks = 0; ks < NSTEP; ++ks) {
        // ---- convert + square-accumulate + LDS write of step ks ----
        bf16x8 av, bv0, bv1;
        cvt_sq(a0, a1, av, accA);
        cvt_sq(b0, b1, bv0, accB);
        cvt_sq(b2, b3, bv1, accB);
        *(bf16x8*)&As[arow][ac8]      = av;
        *(bf16x8*)&Bs[brow][bc16]     = bv0;
        *(bf16x8*)&Bs[brow][bc16 + 8] = bv1;
        __syncthreads();

        // ---- issue global loads for step ks+1 (hide under MFMA) ----
        if (ks + 1 < NSTEP) {
            const float* ap = agp + (ks + 1) * BK;
            const float* bp = bgp + (ks + 1) * BK;
            a0 = ld4(ap); a1 = ld4(ap + 4);
            b0 = ld4(bp);     b1 = ld4(bp + 4);
            b2 = ld4(bp + 8); b3 = ld4(bp + 12);
        }

        // ---- fragments + MFMA ----
        bf16x8 af[4], bf[4];
#pragma unroll
        for (int mi = 0; mi < 4; ++mi)
            af[mi] = *(const bf16x8*)&As[wm * 64 + mi * 16 + l16][g * 8];
#pragma unroll
        for (int nj = 0; nj < 4; ++nj)
            bf[nj] = *(const bf16x8*)&Bs[wn * 64 + nj * 16 + l16][g * 8];
#pragma unroll
        for (int mi = 0; mi < 4; ++mi)
#pragma unroll
            for (int nj = 0; nj < 4; ++nj)
                acc[mi][nj] = __builtin_amdgcn_mfma_f32_16x16x32_bf16(
                    af[mi], bf[nj], acc[mi][nj], 0, 0, 0);
        __syncthreads();
    }

    // ---- norms: reduce per-thread square partials, publish to LDS ----
    accA += __shfl_xor(accA, 1);
    accA += __shfl_xor(accA, 2);
    if ((t & 3) == 0) x2s[arow] = accA;

    accB += __shfl_xor(accB, 1);
    if ((t & 1) == 0) c2s[brow] = accB;
    __syncthreads();

    // ---- epilogue: q = 1/(1+d), row sums, normalize, store ----
    float c2v[4];
#pragma unroll
    for (int nj = 0; nj < 4; ++nj)
        c2v[nj] = c2s[wn * 64 + nj * 16 + l16];

#pragma unroll
    for (int mi = 0; mi < 4; ++mi) {
        const int rbase = wm * 64 + mi * 16 + g * 4;
#pragma unroll
        for (int r = 0; r < 4; ++r) {
            const int row = rbase + r;
            const float x2r = x2s[row];
            float s = 0.f;
#pragma unroll
            for (int nj = 0; nj < 4; ++nj) {
                float d = x2r + c2v[nj] - 2.f * acc[mi][nj][r];
                float q = 1.f / (1.f + d);
                acc[mi][nj][r] = q;
                s += q;
            }
            s += __shfl_xor(s, 1);
            s += __shfl_xor(s, 2);
            s += __shfl_xor(s, 4);
            s += __shfl_xor(s, 8);
            if (l16 == 0) rowsum4[row][wn] = s;
        }
    }
    __syncthreads();

#pragma unroll
    for (int mi = 0; mi < 4; ++mi) {
        const int rbase = wm * 64 + mi * 16 + g * 4;
#pragma unroll
        for (int r = 0; r < 4; ++r) {
            const int row = rbase + r;
            const float inv = 1.f / (rowsum4[row][0] + rowsum4[row][1] +
                                     rowsum4[row][2] + rowsum4[row][3]);
            float* orow = out + (row0 + (size_t)row) * KC;
#pragma unroll
            for (int nj = 0; nj < 4; ++nj)
                orow[wn * 64 + nj * 16 + l16] = acc[mi][nj][r] * inv;
        }
    }
}

extern "C" void kernel_launch(void* const* d_in, const int* in_sizes, int n_in,
                              void* d_out, int out_size, void* d_ws, size_t ws_size,
                              hipStream_t stream) {
    const float* ctx  = (const float*)d_in[0];
    const float* clus = (const float*)d_in[1];
    float* out = (float*)d_out;

    const int nrows = in_sizes[0] / DD;      // 524288
    const int grid  = nrows / BM;            // 4096

    hipLaunchKernelGGL(cluster_q_kernel, dim3(grid), dim3(512), 0, stream,
                       ctx, clus, out);
}

// Round 2
// 520.434 us; speedup vs baseline: 2.2124x; 2.2124x over previous
//
#include <hip/hip_runtime.h>
#include <hip/hip_bf16.h>

// clusterLayer: q = rownorm( 1 / (1 + ||x||^2 + ||c||^2 - 2 x.cT) )
// N=524288, K=256, D=256. fp32 in/out.
// Kernel 0: clusters fp32 -> bf16 padded image (528-B rows) in ws + c2 norms.
// Main: full bf16 clusters in LDS (once), A streamed global->reg->bf16,
// mfma_f32_32x32x16_bf16, full-line stores, in-wave row normalization.

#define DD 256
#define KC 256
#define BM 256
#define BROW 264                     // padded cluster row in shorts (528 B)
#define CL_BYTES (KC * BROW * 2)     // 135168 B

typedef __attribute__((ext_vector_type(4)))  float f32x4;
typedef __attribute__((ext_vector_type(16))) float f32x16;
typedef __attribute__((ext_vector_type(8)))  short bf16x8;
typedef __attribute__((ext_vector_type(4)))  short bf16x4;

__device__ __forceinline__ short f2bf(float f) {
    // round-to-nearest-even fp32 -> bf16
    union { float f; unsigned u; } v; v.f = f;
    unsigned r = (v.u + 0x7fffu + ((v.u >> 16) & 1u)) >> 16;
    return (short)r;
}

__device__ __forceinline__ void gll16(const void* g, void* l) {
    __builtin_amdgcn_global_load_lds(
        (const __attribute__((address_space(1))) void*)g,
        (__attribute__((address_space(3))) void*)l, 16, 0, 0);
}

// ---------------- Kernel 0: prep clusters ----------------
__global__ __launch_bounds__(64)
void prep_clusters(const float* __restrict__ clus,
                   short* __restrict__ wsb, float* __restrict__ c2) {
    const int b = blockIdx.x;      // cluster index 0..255
    const int t = threadIdx.x;     // 0..63
    f32x4 v = *(const f32x4*)(clus + b * DD + t * 4);
    bf16x4 o;
    o[0] = f2bf(v[0]); o[1] = f2bf(v[1]); o[2] = f2bf(v[2]); o[3] = f2bf(v[3]);
    *(bf16x4*)&wsb[b * BROW + t * 4] = o;
    float s = v[0]*v[0] + v[1]*v[1] + v[2]*v[2] + v[3]*v[3];
    s += __shfl_xor(s, 1);  s += __shfl_xor(s, 2);  s += __shfl_xor(s, 4);
    s += __shfl_xor(s, 8);  s += __shfl_xor(s, 16); s += __shfl_xor(s, 32);
    if (t == 0) c2[b] = s;
}

// ---------------- Main kernel ----------------
__global__ __launch_bounds__(512, 2)
void cluster_q_main(const float* __restrict__ ctx,
                    const short* __restrict__ wsb,
                    const float* __restrict__ c2g,
                    float* __restrict__ out) {
    __shared__ short Bs[KC][BROW];           // 132 KiB, rows 528 B (bank-friendly)

    const int t    = threadIdx.x;
    const int lane = t & 63;
    const int w    = t >> 6;                 // wave 0..7, owns rows w*32..w*32+31
    const int l31  = lane & 31;
    const int hi   = lane >> 5;              // 0..1 (k-half)
    const size_t row0 = (size_t)blockIdx.x * BM;

    // ---- stage bf16 cluster image (incl. pad) into LDS, linear copy ----
    {
        const char* src = (const char*)wsb;
        char* dst = (char*)&Bs[0][0];
#pragma unroll
        for (int i = 0; i < 16; ++i)
            gll16(src + i * 8192 + t * 16, dst + i * 8192 + t * 16);
        if (t < 256)
            gll16(src + 131072 + t * 16, dst + 131072 + t * 16);
    }

    // ---- per-lane context slice: row (w*32+l31), k-chunks hi*8 + ks*16 ----
    const float* arow = ctx + (row0 + (size_t)(w * 32 + l31)) * DD + hi * 8;

    // 4-deep rotating prefetch (8 floats = 32 B per k-step per lane)
    f32x4 pa[4], pb[4];
#pragma unroll
    for (int p = 0; p < 4; ++p) {
        pa[p] = *(const f32x4*)(arow + p * 16);
        pb[p] = *(const f32x4*)(arow + p * 16 + 4);
    }

    __syncthreads();   // clusters resident in LDS (drains vmcnt)

    f32x16 acc[8];
#pragma unroll
    for (int nj = 0; nj < 8; ++nj) acc[nj] = (f32x16)0.f;

    float x2p = 0.f;   // partial |x|^2 of row (w*32+l31), this lane's half

#pragma unroll
    for (int ks = 0; ks < 16; ++ks) {
        f32x4 a0 = pa[ks & 3], a1 = pb[ks & 3];
        bf16x8 af;
        af[0] = f2bf(a0[0]); af[1] = f2bf(a0[1]);
        af[2] = f2bf(a0[2]); af[3] = f2bf(a0[3]);
        af[4] = f2bf(a1[0]); af[5] = f2bf(a1[1]);
        af[6] = f2bf(a1[2]); af[7] = f2bf(a1[3]);
        x2p += a0[0]*a0[0] + a0[1]*a0[1] + a0[2]*a0[2] + a0[3]*a0[3]
             + a1[0]*a1[0] + a1[1]*a1[1] + a1[2]*a1[2] + a1[3]*a1[3];

        if (ks < 12) {   // issue k-step ks+4 loads (hide HBM latency)
            pa[ks & 3] = *(const f32x4*)(arow + (ks + 4) * 16);
            pb[ks & 3] = *(const f32x4*)(arow + (ks + 4) * 16 + 4);
        }

#pragma unroll
        for (int nj = 0; nj < 8; ++nj) {
            // B-frag: col = nj*32+l31 (cluster), k = ks*16 + hi*8 .. +8
            bf16x8 bfr = *(const bf16x8*)&Bs[nj * 32 + l31][ks * 16 + hi * 8];
            acc[nj] = __builtin_amdgcn_mfma_f32_32x32x16_bf16(af, bfr, acc[nj], 0, 0, 0);
        }
    }

    // ---- full-row |x|^2: combine the two k-halves (lanes l, l^32) ----
    x2p += __shfl_xor(x2p, 32);

    // cluster norms for this lane's output columns (L2-resident)
    float c2v[8];
#pragma unroll
    for (int nj = 0; nj < 8; ++nj) c2v[nj] = c2g[nj * 32 + l31];

    // ---- epilogue: q, per-row sum (in-wave), normalize, full-line stores ----
#pragma unroll
    for (int r = 0; r < 16; ++r) {
        const int rr = (r & 3) + 8 * (r >> 2) + 4 * hi;   // output row within 32
        const float x2r = __shfl(x2p, rr);                // lane rr holds row rr's |x|^2
        float s = 0.f;
#pragma unroll
        for (int nj = 0; nj < 8; ++nj) {
            float d = x2r + c2v[nj] - 2.f * acc[nj][r];
            float q = 1.f / (1.f + d);
            acc[nj][r] = q;
            s += q;
        }
        s += __shfl_xor(s, 1);
        s += __shfl_xor(s, 2);
        s += __shfl_xor(s, 4);
        s += __shfl_xor(s, 8);
        s += __shfl_xor(s, 16);
        const float inv = 1.f / s;

        float* op = out + (row0 + (size_t)(w * 32 + rr)) * KC + l31;
#pragma unroll
        for (int nj = 0; nj < 8; ++nj)
            op[nj * 32] = acc[nj][r] * inv;   // 2 rows x 128 B full lines / instr
    }
}

extern "C" void kernel_launch(void* const* d_in, const int* in_sizes, int n_in,
                              void* d_out, int out_size, void* d_ws, size_t ws_size,
                              hipStream_t stream) {
    const float* ctx  = (const float*)d_in[0];
    const float* clus = (const float*)d_in[1];
    float* out = (float*)d_out;

    short* wsb = (short*)d_ws;                          // bf16 padded cluster image
    float* c2  = (float*)((char*)d_ws + CL_BYTES);      // 256 fp32 norms

    const int nrows = in_sizes[0] / DD;                 // 524288
    const int grid  = nrows / BM;                       // 2048

    hipLaunchKernelGGL(prep_clusters, dim3(KC), dim3(64), 0, stream, clus, wsb, c2);
    hipLaunchKernelGGL(cluster_q_main, dim3(grid), dim3(512), 0, stream,
                       ctx, wsb, c2, out);
}

// Round 3
// 459.766 us; speedup vs baseline: 2.5044x; 1.1320x over previous
//
#include <hip/hip_runtime.h>
#include <hip/hip_bf16.h>

// clusterLayer: q = rownorm( 1 / (1 + ||x||^2 + ||c||^2 - 2 x.cT) )
// N=524288, K=256, D=256. fp32 in/out.
// Kernel 0: clusters fp32 -> bf16 in MFMA-fragment order (1 KiB per
//   (nj,ks) fragment, lane-contiguous) + fp32 c2 norms, in d_ws.
// Main: NO LDS, NO barriers. B-fragments global-loaded (L2-resident,
//   perfectly coalesced), A streamed global->reg->bf16 with rotating
//   prefetch, mfma_f32_32x32x16_bf16, in-wave normalization,
//   full-line stores. 2 blocks/CU for phase overlap.

#define DD 256
#define KC 256
#define BM 256
#define CL_SHORTS (KC * DD)            // 65536 shorts = 131072 B

typedef __attribute__((ext_vector_type(4)))  float f32x4;
typedef __attribute__((ext_vector_type(16))) float f32x16;
typedef __attribute__((ext_vector_type(8)))  short bf16x8;
typedef __attribute__((ext_vector_type(4)))  short bf16x4;

__device__ __forceinline__ short f2bf(float f) {
    union { float f; unsigned u; } v; v.f = f;
    unsigned r = (v.u + 0x7fffu + ((v.u >> 16) & 1u)) >> 16;
    return (short)r;
}

// ---------------- Kernel 0: prep clusters (fragment-order bf16 + norms) ----
__global__ __launch_bounds__(64)
void prep_clusters(const float* __restrict__ clus,
                   short* __restrict__ wsb, float* __restrict__ c2) {
    const int c = blockIdx.x;      // cluster row 0..255
    const int t = threadIdx.x;     // 0..63, 4 floats each
    f32x4 v = *(const f32x4*)(clus + c * DD + t * 4);
    bf16x4 o;
    o[0] = f2bf(v[0]); o[1] = f2bf(v[1]); o[2] = f2bf(v[2]); o[3] = f2bf(v[3]);

    // fragment layout: frag(nj,ks) is 512 contiguous shorts; within it,
    // lane (hi*32+l31) holds clusters[nj*32+l31][ks*16+hi*8 .. +8].
    const int j    = t >> 1;       // 8-elem chunk index within row (k/8)
    const int ks   = j >> 1;
    const int hi   = j & 1;
    const int half = t & 1;        // which 4-elem half of the chunk
    const int nj   = c >> 5;
    const int l31  = c & 31;
    *(bf16x4*)&wsb[(((nj * 16 + ks) * 64 + hi * 32 + l31) << 3) + half * 4] = o;

    float s = v[0]*v[0] + v[1]*v[1] + v[2]*v[2] + v[3]*v[3];
    s += __shfl_xor(s, 1);  s += __shfl_xor(s, 2);  s += __shfl_xor(s, 4);
    s += __shfl_xor(s, 8);  s += __shfl_xor(s, 16); s += __shfl_xor(s, 32);
    if (t == 0) c2[c] = s;
}

// ---------------- Main kernel ----------------
__global__ __launch_bounds__(512, 2)
void cluster_q_main(const float* __restrict__ ctx,
                    const short* __restrict__ wsb,
                    const float* __restrict__ c2g,
                    float* __restrict__ out) {
    const int t    = threadIdx.x;
    const int lane = t & 63;
    const int w    = t >> 6;                 // wave 0..7 owns rows w*32..+31
    const int l31  = lane & 31;
    const int hi   = lane >> 5;
    const size_t row0 = (size_t)blockIdx.x * BM;

    const float* arow = ctx + (row0 + (size_t)(w * 32 + l31)) * DD + hi * 8;
    const short* bl   = wsb + lane * 8;      // + (nj*16+ks)*512

    // A rotating prefetch, depth 4 (32 B / lane / step)
    f32x4 pa[4], pb[4];
#pragma unroll
    for (int p = 0; p < 4; ++p) {
        pa[p] = *(const f32x4*)(arow + p * 16);
        pb[p] = *(const f32x4*)(arow + p * 16 + 4);
    }

    // B ping-pong prefetch, 1 step ahead
    bf16x8 bA[8], bB[8];
#pragma unroll
    for (int nj = 0; nj < 8; ++nj)
        bA[nj] = *(const bf16x8*)(bl + (nj * 16 + 0) * 512);

    f32x16 acc[8];
#pragma unroll
    for (int nj = 0; nj < 8; ++nj) acc[nj] = (f32x16)0.f;

    float x2p = 0.f;

#pragma unroll
    for (int ks = 0; ks < 16; ++ks) {
        const bool even = (ks & 1) == 0;     // compile-time after unroll

        // issue next-step B loads (fill the other ping-pong bank)
        if (ks < 15) {
#pragma unroll
            for (int nj = 0; nj < 8; ++nj) {
                bf16x8 v = *(const bf16x8*)(bl + (nj * 16 + ks + 1) * 512);
                if (even) bB[nj] = v; else bA[nj] = v;
            }
        }

        // convert A chunk, accumulate |x|^2
        f32x4 a0 = pa[ks & 3], a1 = pb[ks & 3];
        bf16x8 af;
        af[0] = f2bf(a0[0]); af[1] = f2bf(a0[1]);
        af[2] = f2bf(a0[2]); af[3] = f2bf(a0[3]);
        af[4] = f2bf(a1[0]); af[5] = f2bf(a1[1]);
        af[6] = f2bf(a1[2]); af[7] = f2bf(a1[3]);
        x2p += a0[0]*a0[0] + a0[1]*a0[1] + a0[2]*a0[2] + a0[3]*a0[3]
             + a1[0]*a1[0] + a1[1]*a1[1] + a1[2]*a1[2] + a1[3]*a1[3];

        // issue A loads for step ks+4
        if (ks < 12) {
            pa[ks & 3] = *(const f32x4*)(arow + (ks + 4) * 16);
            pb[ks & 3] = *(const f32x4*)(arow + (ks + 4) * 16 + 4);
        }

        // MFMA chain on current bank
#pragma unroll
        for (int nj = 0; nj < 8; ++nj) {
            bf16x8 bfr = even ? bA[nj] : bB[nj];
            acc[nj] = __builtin_amdgcn_mfma_f32_32x32x16_bf16(af, bfr, acc[nj], 0, 0, 0);
        }
    }

    // full-row |x|^2 (combine the two k-halves: lanes l and l^32)
    x2p += __shfl_xor(x2p, 32);

    float c2v[8];
#pragma unroll
    for (int nj = 0; nj < 8; ++nj) c2v[nj] = c2g[nj * 32 + l31];

    // epilogue: q, in-wave row sums, normalize, full-line stores
#pragma unroll
    for (int r = 0; r < 16; ++r) {
        const int rr = (r & 3) + 8 * (r >> 2) + 4 * hi;
        const float x2r = __shfl(x2p, rr);
        float s = 0.f;
#pragma unroll
        for (int nj = 0; nj < 8; ++nj) {
            float d = x2r + c2v[nj] - 2.f * acc[nj][r];
            float q = 1.f / (1.f + d);
            acc[nj][r] = q;
            s += q;
        }
        s += __shfl_xor(s, 1);
        s += __shfl_xor(s, 2);
        s += __shfl_xor(s, 4);
        s += __shfl_xor(s, 8);
        s += __shfl_xor(s, 16);
        const float inv = 1.f / s;

        float* op = out + (row0 + (size_t)(w * 32 + rr)) * KC + l31;
#pragma unroll
        for (int nj = 0; nj < 8; ++nj)
            op[nj * 32] = acc[nj][r] * inv;   // 2 x 128-B full lines / instr
    }
}

extern "C" void kernel_launch(void* const* d_in, const int* in_sizes, int n_in,
                              void* d_out, int out_size, void* d_ws, size_t ws_size,
                              hipStream_t stream) {
    const float* ctx  = (const float*)d_in[0];
    const float* clus = (const float*)d_in[1];
    float* out = (float*)d_out;

    short* wsb = (short*)d_ws;                               // bf16 fragment image
    float* c2  = (float*)((char*)d_ws + CL_SHORTS * 2);      // 256 fp32 norms

    const int nrows = in_sizes[0] / DD;                      // 524288
    const int grid  = nrows / BM;                            // 2048

    hipLaunchKernelGGL(prep_clusters, dim3(KC), dim3(64), 0, stream, clus, wsb, c2);
    hipLaunchKernelGGL(cluster_q_main, dim3(grid), dim3(512), 0, stream,
                       ctx, wsb, c2, out);
}